// Round 7
// baseline (255.673 us; speedup 1.0000x reference)
//
#include <hip/hip_runtime.h>
#include <hip/hip_bf16.h>

// Fused 3-layer tanh RNN (B=131072, T=6, V=31) + linear + tanh + softmax
// on mfma_f32_16x16x32_bf16.
//
// R12: maximize memory-level parallelism -- issue ALL input loads up front.
//
// Little's-law audit of R5-R11: every structure kept ~262 KB of HBM reads
// in flight chip-wide (prefetch depth never changed, only row placement),
// and every one measured 0.9-1.2 TB/s = 262KB / ~240ns HBM latency. The
// kernel is latency x MLP bound; ILP/occupancy/issue/cache changes were
// all null because none raised outstanding bytes. This round: all 12
// x-loads (6 t x 2 rows) + 6 h0-loads issue back-to-back at wave start
// (576 B/lane in flight, ~6x deeper), then the recurrence is pure-register.
//
// Reverted from R11: nontemporal stores (FETCH unchanged, WRITE rose
// 15.9->23.3 MB from partial-line HBM writes, dur flat -> theory dead).
//
// Carried from R7 (best, 82.5us): operand-swap + static W-row permutation
//   D[n][b] = mfma(A = permuted-W-frag, B = state-frag)
// C output IS the next step's B-fragment after tanh+pack; no LDS, no
// shuffles, no barriers. Bias rides the k=31 pad slot (x-frags carry 1.0
// there; pad row (q3,c1[3]) forced to 1.0; Whh frags hold 0 at k=31).
// 2 tiles/wave, 4 waves/block, grid 1024.
//
// VGPR: expect ~180-230 (18 raw8 in flight at peak). launch_bounds(256,1)
// caps at 256. Watch WRITE_SIZE == 15.9 MB as the no-spill signature; if
// spill appears, back off to 3-deep prefetch.
// All t-indexed arrays are fully unrolled -> static indices (no scratch).

#define VD 31
#define TD 6

typedef __attribute__((ext_vector_type(8))) short bf16x8;
typedef __attribute__((ext_vector_type(4))) float f32x4;
typedef __attribute__((ext_vector_type(4))) unsigned u32x4;
typedef float f32x4u __attribute__((ext_vector_type(4), aligned(4)));

struct raw8 { f32x4u a, b; };

__device__ __forceinline__ short f2bf(float f) {
    unsigned u = __float_as_uint(f);
    unsigned r = (u + 0x7fffu + ((u >> 16) & 1u)) >> 16;
    return (short)r;
}

// packed RNE fp32x2 -> bf16x2 (low = lo, high = hi)
__device__ __forceinline__ unsigned f2bf2u(float lo, float hi) {
    union { __hip_bfloat162 h2; unsigned u; } cvt;
    cvt.h2 = __float22bfloat162_rn(make_float2(lo, hi));
    return cvt.u;
}

__device__ __forceinline__ float fast_tanh(float x) {
    x = fminf(fmaxf(x, -15.0f), 15.0f);
    float e = __expf(2.0f * x);
    return (e - 1.0f) * __builtin_amdgcn_rcpf(e + 1.0f);
}

// raw 8-float load at fo = quad3 ? 23 : quad*8 (always in-bounds, 4B aligned)
__device__ __forceinline__ raw8 load_raw(const float* __restrict__ p, int fo) {
    raw8 r;
    r.a = *(const f32x4u*)(p + fo);
    r.b = *(const f32x4u*)(p + fo + 4);
    return r;
}

// raw floats -> B-fragment (lane&15 = batch col, k = quad*8+j). Quad 3
// shifts by one and sets the k=31 pad slot to 1.0 (the bias rides there).
__device__ __forceinline__ bf16x8 cvt_frag(raw8 r, bool q3) {
    float l[8] = {r.a[0], r.a[1], r.a[2], r.a[3], r.b[0], r.b[1], r.b[2], r.b[3]};
    float s[8];
#pragma unroll
    for (int j = 0; j < 7; ++j) s[j] = q3 ? l[j + 1] : l[j];
    s[7] = q3 ? 1.0f : l[7];
    union { u32x4 u4; bf16x8 b8; } cvt;
#pragma unroll
    for (int j = 0; j < 4; ++j) cvt.u4[j] = f2bf2u(s[2 * j], s[2 * j + 1]);
    return cvt.b8;
}

// Permuted-row weight A-fragment: A-row i of the {half} MFMA holds W row
// nn = 8*(i>>2)+(i&3)+4*half, so the C output lands pre-transposed for the
// next step's B-fragment. k=31 slot carries bf16(b1[nn]+b2[nn]); the pad
// row nn==31 is all zero (its output is overridden to 1.0 in layer_step).
__device__ __forceinline__ bf16x8 load_wfrag(const float* __restrict__ W,
                                             const float* __restrict__ b1,
                                             const float* __restrict__ b2,
                                             int i, int half, int k0) {
    const int nn = 8 * (i >> 2) + (i & 3) + 4 * half;
    bf16x8 r;
#pragma unroll
    for (int j = 0; j < 8; ++j) {
        int k = k0 + j;
        float v = 0.0f;
        if (nn < VD) {
            if (k < VD) v = W[nn * VD + k];
            else v = (b1 ? b1[nn] : 0.0f) + (b2 ? b2[nn] : 0.0f);  // k==31
        }
        r[j] = f2bf(v);
    }
    return r;
}

// One RNN layer step for one 16-row tile: 4 MFMA + 8 tanh + 4 cvt_pk.
// Returns the new h directly as the next B-fragment. Pad row (q3, c1[3])
// is forced to 1.0 (bias rider for the consumer's k=31 slot).
__device__ __forceinline__ bf16x8 layer_step(bf16x8 x, bf16x8 h,
    bf16x8 wi0, bf16x8 wi1, bf16x8 wh0, bf16x8 wh1, bool q3)
{
    const f32x4 z = {0.0f, 0.0f, 0.0f, 0.0f};
    f32x4 c0 = __builtin_amdgcn_mfma_f32_16x16x32_bf16(wh0, h, z, 0, 0, 0);
    f32x4 c1 = __builtin_amdgcn_mfma_f32_16x16x32_bf16(wh1, h, z, 0, 0, 0);
    c0 = __builtin_amdgcn_mfma_f32_16x16x32_bf16(wi0, x, c0, 0, 0, 0);
    c1 = __builtin_amdgcn_mfma_f32_16x16x32_bf16(wi1, x, c1, 0, 0, 0);
    float t0 = fast_tanh(c0[0]), t1 = fast_tanh(c0[1]);
    float t2 = fast_tanh(c0[2]), t3 = fast_tanh(c0[3]);
    float t4 = fast_tanh(c1[0]), t5 = fast_tanh(c1[1]);
    float t6 = fast_tanh(c1[2]);
    float t7 = q3 ? 1.0f : fast_tanh(c1[3]);
    union { u32x4 u4; bf16x8 b8; } cvt;
    cvt.u4[0] = f2bf2u(t0, t1);
    cvt.u4[1] = f2bf2u(t2, t3);
    cvt.u4[2] = f2bf2u(t4, t5);
    cvt.u4[3] = f2bf2u(t6, t7);
    return cvt.b8;
}

__global__ __launch_bounds__(256, 1) void rnn_mfma(
    const float* __restrict__ inp,   // [B, T, V]
    const float* __restrict__ h0,    // [L, B, V]
    const float* __restrict__ Wih,   // [L, V, V]
    const float* __restrict__ Whh,   // [L, V, V]
    const float* __restrict__ bih,   // [L, V]
    const float* __restrict__ bhh,   // [L, V]
    const float* __restrict__ Wlin,  // [V, V]
    const float* __restrict__ blin,  // [V]
    float* __restrict__ out,         // [B, V]
    int B)
{
    const int wave = threadIdx.x >> 6;
    const int lane = threadIdx.x & 63;
    const int cb   = lane & 15;          // batch column within the 16-row tile
    const int quad = lane >> 4;
    const int k0   = quad * 8;
    const bool q3  = (quad == 3);
    const int fo   = q3 ? 23 : k0;
    const int bbase = (blockIdx.x * 4 + wave) * 32;   // 32 rows per wave
    if (bbase >= B) return;

    // ---- ISSUE ALL HBM LOADS FIRST (the R12 change): 12 x-loads + 6
    //      h0-loads back-to-back = 576 B/lane outstanding, ~6x the MLP of
    //      R7's rolling 2-deep prefetch. Nothing below depends on them
    //      until the conversions, so they all stay in flight together. ----
    const float* xrow0 = inp + (size_t)(bbase + cb) * TD * VD;
    const float* xrow1 = inp + (size_t)(bbase + 16 + cb) * TD * VD;

    raw8 xr[TD][2];
#pragma unroll
    for (int t = 0; t < TD; ++t) {
        xr[t][0] = load_raw(xrow0 + t * VD, fo);
        xr[t][1] = load_raw(xrow1 + t * VD, fo);
    }
    raw8 h1ra = load_raw(h0 + ((size_t)0 * B + bbase + cb) * VD, fo);
    raw8 h1rb = load_raw(h0 + ((size_t)0 * B + bbase + 16 + cb) * VD, fo);
    raw8 h2ra = load_raw(h0 + ((size_t)1 * B + bbase + cb) * VD, fo);
    raw8 h2rb = load_raw(h0 + ((size_t)1 * B + bbase + 16 + cb) * VD, fo);
    raw8 h3ra = load_raw(h0 + ((size_t)2 * B + bbase + cb) * VD, fo);
    raw8 h3rb = load_raw(h0 + ((size_t)2 * B + bbase + 16 + cb) * VD, fo);

    // ---- stationary permuted weight A-fragments (56 VGPRs): L2-resident
    //      gathers, issued after the HBM-critical loads above ----
    const float* W0 = Wih;               const float* U0 = Whh;
    const float* W1 = Wih + VD * VD;     const float* U1 = Whh + VD * VD;
    const float* W2 = Wih + 2 * VD * VD; const float* U2 = Whh + 2 * VD * VD;
    const bf16x8 wiA0 = load_wfrag(W0, bih, bhh, cb, 0, k0);
    const bf16x8 wiA1 = load_wfrag(W0, bih, bhh, cb, 1, k0);
    const bf16x8 whA0 = load_wfrag(U0, nullptr, nullptr, cb, 0, k0);
    const bf16x8 whA1 = load_wfrag(U0, nullptr, nullptr, cb, 1, k0);
    const bf16x8 wiB0 = load_wfrag(W1, bih + VD, bhh + VD, cb, 0, k0);
    const bf16x8 wiB1 = load_wfrag(W1, bih + VD, bhh + VD, cb, 1, k0);
    const bf16x8 whB0 = load_wfrag(U1, nullptr, nullptr, cb, 0, k0);
    const bf16x8 whB1 = load_wfrag(U1, nullptr, nullptr, cb, 1, k0);
    const bf16x8 wiC0 = load_wfrag(W2, bih + 2 * VD, bhh + 2 * VD, cb, 0, k0);
    const bf16x8 wiC1 = load_wfrag(W2, bih + 2 * VD, bhh + 2 * VD, cb, 1, k0);
    const bf16x8 whC0 = load_wfrag(U2, nullptr, nullptr, cb, 0, k0);
    const bf16x8 whC1 = load_wfrag(U2, nullptr, nullptr, cb, 1, k0);
    const bf16x8 wl0  = load_wfrag(Wlin, blin, nullptr, cb, 0, k0);
    const bf16x8 wl1  = load_wfrag(Wlin, blin, nullptr, cb, 1, k0);

    // ---- convert in load order (oldest first): raws freed progressively,
    //      x held as compact bf16 frags (4 VGPR each) ----
    bf16x8 ax[TD][2];
#pragma unroll
    for (int t = 0; t < TD; ++t) {
        ax[t][0] = cvt_frag(xr[t][0], q3);
        ax[t][1] = cvt_frag(xr[t][1], q3);
    }
    bf16x8 h1a = cvt_frag(h1ra, q3), h1b = cvt_frag(h1rb, q3);
    bf16x8 h2a = cvt_frag(h2ra, q3), h2b = cvt_frag(h2rb, q3);
    bf16x8 h3a = cvt_frag(h3ra, q3), h3b = cvt_frag(h3rb, q3);

    // ---- pure-register t-major recurrence (no memory ops at all) ----
#pragma unroll
    for (int t = 0; t < TD; ++t) {
        h1a = layer_step(ax[t][0], h1a, wiA0, wiA1, whA0, whA1, q3);
        h1b = layer_step(ax[t][1], h1b, wiA0, wiA1, whA0, whA1, q3);
        h2a = layer_step(h1a, h2a, wiB0, wiB1, whB0, whB1, q3);
        h2b = layer_step(h1b, h2b, wiB0, wiB1, whB0, whB1, q3);
        h3a = layer_step(h2a, h3a, wiC0, wiC1, whC0, whC1, q3);
        h3b = layer_step(h2b, h3b, wiC0, wiC1, whC0, whC1, q3);
    }

    // ---- final linear + tanh + softmax (normal stores; NT reverted) ----
    const f32x4 z = {0.0f, 0.0f, 0.0f, 0.0f};
#pragma unroll
    for (int tb = 0; tb < 2; ++tb) {
        bf16x8 h3 = tb ? h3b : h3a;
        f32x4 c0 = __builtin_amdgcn_mfma_f32_16x16x32_bf16(wl0, h3, z, 0, 0, 0);
        f32x4 c1 = __builtin_amdgcn_mfma_f32_16x16x32_bf16(wl1, h3, z, 0, 0, 0);
        // lane (cb, q) holds y[n] for n = 8q..8q+7; n==31 (q3, c1[3]) is the
        // pad row -> y = tanh(0) = 0, excluded from the sum (harmless in max:
        // the stabilizer just needs to be column-uniform).
        float v0 = fast_tanh(c0[0]), v1 = fast_tanh(c0[1]);
        float v2 = fast_tanh(c0[2]), v3 = fast_tanh(c0[3]);
        float v4 = fast_tanh(c1[0]), v5 = fast_tanh(c1[1]);
        float v6 = fast_tanh(c1[2]), v7 = fast_tanh(c1[3]);
        float mx = fmaxf(fmaxf(fmaxf(v0, v1), fmaxf(v2, v3)),
                         fmaxf(fmaxf(v4, v5), fmaxf(v6, v7)));
        mx = fmaxf(mx, __shfl_xor(mx, 16));
        mx = fmaxf(mx, __shfl_xor(mx, 32));
        float e0 = __expf(v0 - mx), e1 = __expf(v1 - mx);
        float e2 = __expf(v2 - mx), e3 = __expf(v3 - mx);
        float e4 = __expf(v4 - mx), e5 = __expf(v5 - mx);
        float e6 = __expf(v6 - mx);
        float e7 = q3 ? 0.0f : __expf(v7 - mx);
        float s = ((e0 + e1) + (e2 + e3)) + ((e4 + e5) + (e6 + e7));
        s += __shfl_xor(s, 16);
        s += __shfl_xor(s, 32);
        const float inv = __builtin_amdgcn_rcpf(s);
        const size_t row = (size_t)(bbase + tb * 16 + cb);
        float* po = out + row * VD + k0;            // n = 8q..8q+7, contiguous
        f32x4u lo = {e0 * inv, e1 * inv, e2 * inv, e3 * inv};
        *(f32x4u*)po = lo;
        if (!q3) {
            f32x4u hi = {e4 * inv, e5 * inv, e6 * inv, e7 * inv};
            *(f32x4u*)(po + 4) = hi;
        } else {                                    // n = 28,29,30 only
            po[4] = e4 * inv;
            po[5] = e5 * inv;
            po[6] = e6 * inv;
        }
    }
}

extern "C" void kernel_launch(void* const* d_in, const int* in_sizes, int n_in,
                              void* d_out, int out_size, void* d_ws, size_t ws_size,
                              hipStream_t stream) {
    const float* inp  = (const float*)d_in[0];
    const float* h0   = (const float*)d_in[1];
    const float* Wih  = (const float*)d_in[2];
    const float* Whh  = (const float*)d_in[3];
    const float* bih  = (const float*)d_in[4];
    const float* bhh  = (const float*)d_in[5];
    const float* Wlin = (const float*)d_in[6];
    const float* blin = (const float*)d_in[7];
    float* out = (float*)d_out;

    const int B = in_sizes[0] / (TD * VD);
    const int grid = (B + 127) / 128;    // 128 rows per block (4 waves x 32)
    rnn_mfma<<<grid, 256, 0, stream>>>(inp, h0, Wih, Whh, bih, bhh, Wlin, blin, out, B);
}

// Round 8
// 252.229 us; speedup vs baseline: 1.0137x; 1.0137x over previous
//
#include <hip/hip_runtime.h>
#include <hip/hip_bf16.h>

// Fused 3-layer tanh RNN (B=131072, T=6, V=31) + linear + tanh + softmax
// on mfma_f32_16x16x32_bf16.
//
// R13: double wave-level parallelism by evicting weights from VGPRs.
//
// Causal datum from R12: VGPR 104->144 crossed the 4->3 waves/SIMD
// boundary and dur DOUBLED (83->177us) while bytes and issue count fell.
// Combined with R7-R9 (every VGPR<=120 structure lands at ~83us no matter
// what the inner loop does), the kernel is memory-latency-bound and the
// only effective lever is resident-wave TLP. The 56-VGPR stationary weight
// fragment set is identical for every wave (layout depends only on lane),
// so it moves to LDS:
//   - wave 0 builds all 14 pre-permuted, SCL-scaled bf16 fragments
//     (112 one-time global gathers, 1 wave/block instead of 4) and writes
//     them to a 14KB per-lane table: frag f, lane l at f*1024 + l*16.
//   - every layer step re-reads its 4 fragments with lane-contiguous
//     ds_read_b128 (canonical conflict-free pattern, ~12cy, hidden by TLP).
// 1 tile/wave (16 rows), grid 2048, __launch_bounds__(256,8):
// VGPR target <=64 -> 8 waves/SIMD (2x R7), 8 blocks/CU, LDS 115KB/CU.
//
// Kept: R8's scale-folded tanh_pre (absmax unchanged in R9/R10, saves
// regs+ops): tanh(x) = 1 - 2*rcp(1+exp2(c)), SCL=2*log2(e) folded into
// ALL weight/bias fragments (incl. Wlin; epilogue uses tanh_pre too).
// R7's operand-swap recurrence: D[n][b] = mfma(A=permuted-W, B=state);
// C output IS the next B-fragment after tanh+pack. Bias rides k=31
// (x-frags carry 1.0 there; pad row (q3,c1[3]) forced to 1.0; Whh rows
// hold 0 at k=31). Normal stores (R11's NT stores regressed WRITE).
//
// WATCH: VGPR_Count <= 64 and WRITE_SIZE == 15.9MB (no scratch). If VGPR
// capped with spill -> back off to launch_bounds(256,6) next round.

#define VD 31
#define TD 6
#define SCL 2.8853900817779268f   // 2 * log2(e), folded into W and biases

typedef __attribute__((ext_vector_type(8))) short bf16x8;
typedef __attribute__((ext_vector_type(4))) float f32x4;
typedef __attribute__((ext_vector_type(4))) unsigned u32x4;
typedef float f32x4u __attribute__((ext_vector_type(4), aligned(4)));

struct raw8 { f32x4u a, b; };

__device__ __forceinline__ short f2bf(float f) {
    unsigned u = __float_as_uint(f);
    unsigned r = (u + 0x7fffu + ((u >> 16) & 1u)) >> 16;
    return (short)r;
}

// packed RNE fp32x2 -> bf16x2 (low = lo, high = hi)
__device__ __forceinline__ unsigned f2bf2u(float lo, float hi) {
    union { __hip_bfloat162 h2; unsigned u; } cvt;
    cvt.h2 = __float22bfloat162_rn(make_float2(lo, hi));
    return cvt.u;
}

__device__ __forceinline__ float fexp2(float x) {
#if __has_builtin(__builtin_amdgcn_exp2f)
    return __builtin_amdgcn_exp2f(x);
#else
    float r; asm("v_exp_f32 %0, %1" : "=v"(r) : "v"(x)); return r;
#endif
}

// c = 2*log2e * x (scale pre-folded into weights/biases).
// tanh(x) = 1 - 2/(e^{2x}+1); naturally saturating, no clamp needed.
__device__ __forceinline__ float tanh_pre(float c) {
    float e = fexp2(c);
    float r = __builtin_amdgcn_rcpf(e + 1.0f);
    return __builtin_fmaf(-2.0f, r, 1.0f);
}

// raw 8-float load at fo = quad3 ? 23 : quad*8 (always in-bounds, 4B aligned)
__device__ __forceinline__ raw8 load_raw(const float* __restrict__ p, int fo) {
    raw8 r;
    r.a = *(const f32x4u*)(p + fo);
    r.b = *(const f32x4u*)(p + fo + 4);
    return r;
}

// raw floats -> B-fragment (lane&15 = batch col, k = quad*8+j). Quad 3
// shifts by one and sets the k=31 pad slot to 1.0 (the bias rides there).
__device__ __forceinline__ bf16x8 cvt_frag(raw8 r, bool q3) {
    float l[8] = {r.a[0], r.a[1], r.a[2], r.a[3], r.b[0], r.b[1], r.b[2], r.b[3]};
    float s[8];
#pragma unroll
    for (int j = 0; j < 7; ++j) s[j] = q3 ? l[j + 1] : l[j];
    s[7] = q3 ? 1.0f : l[7];
    union { u32x4 u4; bf16x8 b8; } cvt;
#pragma unroll
    for (int j = 0; j < 4; ++j) cvt.u4[j] = f2bf2u(s[2 * j], s[2 * j + 1]);
    return cvt.b8;
}

// Permuted-row weight A-fragment scaled by SCL (built once by wave 0):
// A-row i of the {half} MFMA holds W row nn = 8*(i>>2)+(i&3)+4*half, so
// the C output lands pre-transposed for the next step's B-fragment.
// k=31 slot carries SCL*(b1[nn]+b2[nn]); pad row nn==31 is all zero.
__device__ __forceinline__ bf16x8 load_wfrag(const float* __restrict__ W,
                                             const float* __restrict__ b1,
                                             const float* __restrict__ b2,
                                             int i, int half, int k0) {
    const int nn = 8 * (i >> 2) + (i & 3) + 4 * half;
    bf16x8 r;
#pragma unroll
    for (int j = 0; j < 8; ++j) {
        int k = k0 + j;
        float v = 0.0f;
        if (nn < VD) {
            if (k < VD) v = W[nn * VD + k];
            else v = (b1 ? b1[nn] : 0.0f) + (b2 ? b2[nn] : 0.0f);  // k==31
        }
        r[j] = f2bf(v * SCL);
    }
    return r;
}

// One RNN layer step for one 16-row tile: 4 MFMA + 8 tanh_pre + 4 cvt_pk.
// Returns the new h directly as the next B-fragment. Pad row (q3, c1[3])
// is forced to 1.0 (bias rider for the consumer's k=31 slot).
__device__ __forceinline__ bf16x8 layer_step(bf16x8 x, bf16x8 h,
    bf16x8 wi0, bf16x8 wi1, bf16x8 wh0, bf16x8 wh1, bool q3)
{
    const f32x4 z = {0.0f, 0.0f, 0.0f, 0.0f};
    f32x4 c0 = __builtin_amdgcn_mfma_f32_16x16x32_bf16(wh0, h, z, 0, 0, 0);
    f32x4 c1 = __builtin_amdgcn_mfma_f32_16x16x32_bf16(wh1, h, z, 0, 0, 0);
    c0 = __builtin_amdgcn_mfma_f32_16x16x32_bf16(wi0, x, c0, 0, 0, 0);
    c1 = __builtin_amdgcn_mfma_f32_16x16x32_bf16(wi1, x, c1, 0, 0, 0);
    float t0 = tanh_pre(c0[0]), t1 = tanh_pre(c0[1]);
    float t2 = tanh_pre(c0[2]), t3 = tanh_pre(c0[3]);
    float t4 = tanh_pre(c1[0]), t5 = tanh_pre(c1[1]);
    float t6 = tanh_pre(c1[2]);
    float t7 = q3 ? 1.0f : tanh_pre(c1[3]);
    union { u32x4 u4; bf16x8 b8; } cvt;
    cvt.u4[0] = f2bf2u(t0, t1);
    cvt.u4[1] = f2bf2u(t2, t3);
    cvt.u4[2] = f2bf2u(t4, t5);
    cvt.u4[3] = f2bf2u(t6, t7);
    return cvt.b8;
}

__global__ __launch_bounds__(256, 8) void rnn_mfma(
    const float* __restrict__ inp,   // [B, T, V]
    const float* __restrict__ h0,    // [L, B, V]
    const float* __restrict__ Wih,   // [L, V, V]
    const float* __restrict__ Whh,   // [L, V, V]
    const float* __restrict__ bih,   // [L, V]
    const float* __restrict__ bhh,   // [L, V]
    const float* __restrict__ Wlin,  // [V, V]
    const float* __restrict__ blin,  // [V]
    float* __restrict__ out,         // [B, V]
    int B)
{
    // 14 fragments x 64 lanes x 16B = 14336 B
    __shared__ __align__(16) short wtab[14 * 512];

    const int tid  = threadIdx.x;
    const int wave = tid >> 6;
    const int lane = tid & 63;
    const int cb   = lane & 15;          // batch column within the 16-row tile
    const int quad = lane >> 4;
    const int k0   = quad * 8;
    const bool q3  = (quad == 3);
    const int fo   = q3 ? 23 : k0;
    const int bbase = (blockIdx.x * 4 + wave) * 16;   // 16 rows per wave

    // ---- wave 0 builds the shared per-lane fragment table (one-time
    //      global gathers; 1 wave/block instead of 4) ----
    if (wave == 0) {
        const float* W0 = Wih;               const float* U0 = Whh;
        const float* W1 = Wih + VD * VD;     const float* U1 = Whh + VD * VD;
        const float* W2 = Wih + 2 * VD * VD; const float* U2 = Whh + 2 * VD * VD;
        short* p = wtab + lane * 8;
        *(bf16x8*)(p + 0 * 512)  = load_wfrag(W0, bih, bhh, lane & 15, 0, k0);
        *(bf16x8*)(p + 1 * 512)  = load_wfrag(W0, bih, bhh, lane & 15, 1, k0);
        *(bf16x8*)(p + 2 * 512)  = load_wfrag(U0, nullptr, nullptr, lane & 15, 0, k0);
        *(bf16x8*)(p + 3 * 512)  = load_wfrag(U0, nullptr, nullptr, lane & 15, 1, k0);
        *(bf16x8*)(p + 4 * 512)  = load_wfrag(W1, bih + VD, bhh + VD, lane & 15, 0, k0);
        *(bf16x8*)(p + 5 * 512)  = load_wfrag(W1, bih + VD, bhh + VD, lane & 15, 1, k0);
        *(bf16x8*)(p + 6 * 512)  = load_wfrag(U1, nullptr, nullptr, lane & 15, 0, k0);
        *(bf16x8*)(p + 7 * 512)  = load_wfrag(U1, nullptr, nullptr, lane & 15, 1, k0);
        *(bf16x8*)(p + 8 * 512)  = load_wfrag(W2, bih + 2 * VD, bhh + 2 * VD, lane & 15, 0, k0);
        *(bf16x8*)(p + 9 * 512)  = load_wfrag(W2, bih + 2 * VD, bhh + 2 * VD, lane & 15, 1, k0);
        *(bf16x8*)(p + 10 * 512) = load_wfrag(U2, nullptr, nullptr, lane & 15, 0, k0);
        *(bf16x8*)(p + 11 * 512) = load_wfrag(U2, nullptr, nullptr, lane & 15, 1, k0);
        *(bf16x8*)(p + 12 * 512) = load_wfrag(Wlin, blin, nullptr, lane & 15, 0, k0);
        *(bf16x8*)(p + 13 * 512) = load_wfrag(Wlin, blin, nullptr, lane & 15, 1, k0);
    }
    __syncthreads();
    if (bbase >= B) return;

    const short* tp = wtab + lane * 8;   // this lane's slice of the table
#define LDF(f) (*(const bf16x8*)(tp + (f) * 512))

    // ---- initial hidden states (pad slot is a don't-care at first use:
    //      Whh fragment rows hold 0 at k=31) ----
    bf16x8 h1 = cvt_frag(load_raw(h0 + ((size_t)0 * B + bbase + cb) * VD, fo), q3);
    bf16x8 h2 = cvt_frag(load_raw(h0 + ((size_t)1 * B + bbase + cb) * VD, fo), q3);
    bf16x8 h3 = cvt_frag(load_raw(h0 + ((size_t)2 * B + bbase + cb) * VD, fo), q3);

    const float* xrow = inp + (size_t)(bbase + cb) * TD * VD;
    raw8 rx = load_raw(xrow, fo);

    // ---- t-major recurrence; weights re-read from LDS each step
    //      (lane-contiguous ds_read_b128, conflict-free). unroll 1 keeps
    //      live ranges tight for the <=64-VGPR target. ----
#pragma unroll 1
    for (int t = 0; t < TD; ++t) {
        bf16x8 ax = cvt_frag(rx, q3);
        if (t + 1 < TD)
            rx = load_raw(xrow + (t + 1) * VD, fo);
        h1 = layer_step(ax, h1, LDF(0), LDF(1), LDF(2),  LDF(3),  q3);
        h2 = layer_step(h1, h2, LDF(4), LDF(5), LDF(6),  LDF(7),  q3);
        h3 = layer_step(h2, h3, LDF(8), LDF(9), LDF(10), LDF(11), q3);
    }

    // ---- final linear + tanh + softmax (over n, i.e. across quads) ----
    {
        const f32x4 z = {0.0f, 0.0f, 0.0f, 0.0f};
        bf16x8 wl0 = LDF(12), wl1 = LDF(13);
        f32x4 c0 = __builtin_amdgcn_mfma_f32_16x16x32_bf16(wl0, h3, z, 0, 0, 0);
        f32x4 c1 = __builtin_amdgcn_mfma_f32_16x16x32_bf16(wl1, h3, z, 0, 0, 0);
        // lane (cb, q) holds y[n] for n = 8q..8q+7; n==31 (q3, c1[3]) is the
        // pad row -> tanh_pre(0) = 0, excluded from the sum (harmless in max:
        // the stabilizer just needs to be column-uniform).
        float v0 = tanh_pre(c0[0]), v1 = tanh_pre(c0[1]);
        float v2 = tanh_pre(c0[2]), v3 = tanh_pre(c0[3]);
        float v4 = tanh_pre(c1[0]), v5 = tanh_pre(c1[1]);
        float v6 = tanh_pre(c1[2]), v7 = tanh_pre(c1[3]);
        float mx = fmaxf(fmaxf(fmaxf(v0, v1), fmaxf(v2, v3)),
                         fmaxf(fmaxf(v4, v5), fmaxf(v6, v7)));
        mx = fmaxf(mx, __shfl_xor(mx, 16));
        mx = fmaxf(mx, __shfl_xor(mx, 32));
        float e0 = __expf(v0 - mx), e1 = __expf(v1 - mx);
        float e2 = __expf(v2 - mx), e3 = __expf(v3 - mx);
        float e4 = __expf(v4 - mx), e5 = __expf(v5 - mx);
        float e6 = __expf(v6 - mx);
        float e7 = q3 ? 0.0f : __expf(v7 - mx);
        float s = ((e0 + e1) + (e2 + e3)) + ((e4 + e5) + (e6 + e7));
        s += __shfl_xor(s, 16);
        s += __shfl_xor(s, 32);
        const float inv = __builtin_amdgcn_rcpf(s);
        const size_t row = (size_t)(bbase + cb);
        float* po = out + row * VD + k0;            // n = 8q..8q+7, contiguous
        f32x4u lo = {e0 * inv, e1 * inv, e2 * inv, e3 * inv};
        *(f32x4u*)po = lo;
        if (!q3) {
            f32x4u hi = {e4 * inv, e5 * inv, e6 * inv, e7 * inv};
            *(f32x4u*)(po + 4) = hi;
        } else {                                    // n = 28,29,30 only
            po[4] = e4 * inv;
            po[5] = e5 * inv;
            po[6] = e6 * inv;
        }
    }
#undef LDF
}

extern "C" void kernel_launch(void* const* d_in, const int* in_sizes, int n_in,
                              void* d_out, int out_size, void* d_ws, size_t ws_size,
                              hipStream_t stream) {
    const float* inp  = (const float*)d_in[0];
    const float* h0   = (const float*)d_in[1];
    const float* Wih  = (const float*)d_in[2];
    const float* Whh  = (const float*)d_in[3];
    const float* bih  = (const float*)d_in[4];
    const float* bhh  = (const float*)d_in[5];
    const float* Wlin = (const float*)d_in[6];
    const float* blin = (const float*)d_in[7];
    float* out = (float*)d_out;

    const int B = in_sizes[0] / (TD * VD);
    const int grid = (B + 63) / 64;      // 64 rows per block (4 waves x 16)
    rnn_mfma<<<grid, 256, 0, stream>>>(inp, h0, Wih, Whh, bih, bhh, Wlin, blin, out, B);
}

// Round 9
// 226.698 us; speedup vs baseline: 1.1278x; 1.1126x over previous
//
#include <hip/hip_runtime.h>
#include <hip/hip_bf16.h>

// Fused 3-layer tanh RNN (B=131072, T=6, V=31) + linear + tanh + softmax
// on mfma_f32_16x16x32_bf16.
//
// R14: R13 with the occupancy cap backed off 8 -> 6 waves/SIMD.
//
// R13 proved the diagnosis: occupancy 19->77% moved HBM BW 1.1->2.28 TB/s
// (the ONLY thing in 8 rounds that moved the memory rate) -- the kernel is
// memory-latency-bound and TLP is the lever. But launch_bounds(256,8)
// forced VGPR to 32 and the ~60-VGPR working set spilled to scratch:
// WRITE 15.9->60.9 MB, FETCH 75->200 MB; 268 MB at 2.28 TB/s = 117us.
// Spill-free bytes (~91 MB) at that BW would be ~40us.
//
// R14 changes ONE knob: __launch_bounds__(256,6) -> VGPR budget ~85,
// which fits the working set (state 12 + rx 8 + weight transients 16 +
// acc 8 + addressing ~20). 24 waves/CU, LDS 6x14KB = 86KB/CU.
//
// Carried from R13:
//  - weights OUT of VGPRs: wave 0 builds all 14 pre-permuted, SCL-scaled
//    bf16 fragments in a 14KB LDS table (frag f, lane l at f*1024+l*16);
//    layer steps re-read them with lane-contiguous ds_read_b128
//    (conflict-free, hidden by TLP).
//  - 1 tile/wave (16 rows), grid 2048.
//  - scale-folded tanh_pre: tanh(x) = 1 - 2*rcp(1+exp2(c)), SCL=2*log2e
//    folded into ALL weight/bias fragments (incl. Wlin).
//  - operand-swap recurrence D[n][b] = mfma(A=permuted-W, B=state);
//    C output IS the next B-fragment after tanh+pack. Bias rides k=31
//    (x-frags carry 1.0 there; pad row (q3,c1[3]) forced to 1.0; Whh
//    rows hold 0 at k=31). Normal stores.
//
// WATCH: VGPR_Count 68-85 (32 means spill again), WRITE_SIZE == 15.9 MB
// (no-spill signature), FETCH ~75-95 MB, Occupancy ~55-65%.
// Fallback if spill: launch_bounds(256,5).

#define VD 31
#define TD 6
#define SCL 2.8853900817779268f   // 2 * log2(e), folded into W and biases

typedef __attribute__((ext_vector_type(8))) short bf16x8;
typedef __attribute__((ext_vector_type(4))) float f32x4;
typedef __attribute__((ext_vector_type(4))) unsigned u32x4;
typedef float f32x4u __attribute__((ext_vector_type(4), aligned(4)));

struct raw8 { f32x4u a, b; };

__device__ __forceinline__ short f2bf(float f) {
    unsigned u = __float_as_uint(f);
    unsigned r = (u + 0x7fffu + ((u >> 16) & 1u)) >> 16;
    return (short)r;
}

// packed RNE fp32x2 -> bf16x2 (low = lo, high = hi)
__device__ __forceinline__ unsigned f2bf2u(float lo, float hi) {
    union { __hip_bfloat162 h2; unsigned u; } cvt;
    cvt.h2 = __float22bfloat162_rn(make_float2(lo, hi));
    return cvt.u;
}

__device__ __forceinline__ float fexp2(float x) {
#if __has_builtin(__builtin_amdgcn_exp2f)
    return __builtin_amdgcn_exp2f(x);
#else
    float r; asm("v_exp_f32 %0, %1" : "=v"(r) : "v"(x)); return r;
#endif
}

// c = 2*log2e * x (scale pre-folded into weights/biases).
// tanh(x) = 1 - 2/(e^{2x}+1); naturally saturating, no clamp needed.
__device__ __forceinline__ float tanh_pre(float c) {
    float e = fexp2(c);
    float r = __builtin_amdgcn_rcpf(e + 1.0f);
    return __builtin_fmaf(-2.0f, r, 1.0f);
}

// raw 8-float load at fo = quad3 ? 23 : quad*8 (always in-bounds, 4B aligned)
__device__ __forceinline__ raw8 load_raw(const float* __restrict__ p, int fo) {
    raw8 r;
    r.a = *(const f32x4u*)(p + fo);
    r.b = *(const f32x4u*)(p + fo + 4);
    return r;
}

// raw floats -> B-fragment (lane&15 = batch col, k = quad*8+j). Quad 3
// shifts by one and sets the k=31 pad slot to 1.0 (the bias rides there).
__device__ __forceinline__ bf16x8 cvt_frag(raw8 r, bool q3) {
    float l[8] = {r.a[0], r.a[1], r.a[2], r.a[3], r.b[0], r.b[1], r.b[2], r.b[3]};
    float s[8];
#pragma unroll
    for (int j = 0; j < 7; ++j) s[j] = q3 ? l[j + 1] : l[j];
    s[7] = q3 ? 1.0f : l[7];
    union { u32x4 u4; bf16x8 b8; } cvt;
#pragma unroll
    for (int j = 0; j < 4; ++j) cvt.u4[j] = f2bf2u(s[2 * j], s[2 * j + 1]);
    return cvt.b8;
}

// Permuted-row weight A-fragment scaled by SCL (built once by wave 0):
// A-row i of the {half} MFMA holds W row nn = 8*(i>>2)+(i&3)+4*half, so
// the C output lands pre-transposed for the next step's B-fragment.
// k=31 slot carries SCL*(b1[nn]+b2[nn]); pad row nn==31 is all zero.
__device__ __forceinline__ bf16x8 load_wfrag(const float* __restrict__ W,
                                             const float* __restrict__ b1,
                                             const float* __restrict__ b2,
                                             int i, int half, int k0) {
    const int nn = 8 * (i >> 2) + (i & 3) + 4 * half;
    bf16x8 r;
#pragma unroll
    for (int j = 0; j < 8; ++j) {
        int k = k0 + j;
        float v = 0.0f;
        if (nn < VD) {
            if (k < VD) v = W[nn * VD + k];
            else v = (b1 ? b1[nn] : 0.0f) + (b2 ? b2[nn] : 0.0f);  // k==31
        }
        r[j] = f2bf(v * SCL);
    }
    return r;
}

// One RNN layer step for one 16-row tile: 4 MFMA + 8 tanh_pre + 4 cvt_pk.
// Returns the new h directly as the next B-fragment. Pad row (q3, c1[3])
// is forced to 1.0 (bias rider for the consumer's k=31 slot).
__device__ __forceinline__ bf16x8 layer_step(bf16x8 x, bf16x8 h,
    bf16x8 wi0, bf16x8 wi1, bf16x8 wh0, bf16x8 wh1, bool q3)
{
    const f32x4 z = {0.0f, 0.0f, 0.0f, 0.0f};
    f32x4 c0 = __builtin_amdgcn_mfma_f32_16x16x32_bf16(wh0, h, z, 0, 0, 0);
    f32x4 c1 = __builtin_amdgcn_mfma_f32_16x16x32_bf16(wh1, h, z, 0, 0, 0);
    c0 = __builtin_amdgcn_mfma_f32_16x16x32_bf16(wi0, x, c0, 0, 0, 0);
    c1 = __builtin_amdgcn_mfma_f32_16x16x32_bf16(wi1, x, c1, 0, 0, 0);
    float t0 = tanh_pre(c0[0]), t1 = tanh_pre(c0[1]);
    float t2 = tanh_pre(c0[2]), t3 = tanh_pre(c0[3]);
    float t4 = tanh_pre(c1[0]), t5 = tanh_pre(c1[1]);
    float t6 = tanh_pre(c1[2]);
    float t7 = q3 ? 1.0f : tanh_pre(c1[3]);
    union { u32x4 u4; bf16x8 b8; } cvt;
    cvt.u4[0] = f2bf2u(t0, t1);
    cvt.u4[1] = f2bf2u(t2, t3);
    cvt.u4[2] = f2bf2u(t4, t5);
    cvt.u4[3] = f2bf2u(t6, t7);
    return cvt.b8;
}

__global__ __launch_bounds__(256, 6) void rnn_mfma(
    const float* __restrict__ inp,   // [B, T, V]
    const float* __restrict__ h0,    // [L, B, V]
    const float* __restrict__ Wih,   // [L, V, V]
    const float* __restrict__ Whh,   // [L, V, V]
    const float* __restrict__ bih,   // [L, V]
    const float* __restrict__ bhh,   // [L, V]
    const float* __restrict__ Wlin,  // [V, V]
    const float* __restrict__ blin,  // [V]
    float* __restrict__ out,         // [B, V]
    int B)
{
    // 14 fragments x 64 lanes x 16B = 14336 B
    __shared__ __align__(16) short wtab[14 * 512];

    const int tid  = threadIdx.x;
    const int wave = tid >> 6;
    const int lane = tid & 63;
    const int cb   = lane & 15;          // batch column within the 16-row tile
    const int quad = lane >> 4;
    const int k0   = quad * 8;
    const bool q3  = (quad == 3);
    const int fo   = q3 ? 23 : k0;
    const int bbase = (blockIdx.x * 4 + wave) * 16;   // 16 rows per wave

    // ---- wave 0 builds the shared per-lane fragment table (one-time
    //      global gathers; 1 wave/block instead of 4) ----
    if (wave == 0) {
        const float* W0 = Wih;               const float* U0 = Whh;
        const float* W1 = Wih + VD * VD;     const float* U1 = Whh + VD * VD;
        const float* W2 = Wih + 2 * VD * VD; const float* U2 = Whh + 2 * VD * VD;
        short* p = wtab + lane * 8;
        *(bf16x8*)(p + 0 * 512)  = load_wfrag(W0, bih, bhh, lane & 15, 0, k0);
        *(bf16x8*)(p + 1 * 512)  = load_wfrag(W0, bih, bhh, lane & 15, 1, k0);
        *(bf16x8*)(p + 2 * 512)  = load_wfrag(U0, nullptr, nullptr, lane & 15, 0, k0);
        *(bf16x8*)(p + 3 * 512)  = load_wfrag(U0, nullptr, nullptr, lane & 15, 1, k0);
        *(bf16x8*)(p + 4 * 512)  = load_wfrag(W1, bih + VD, bhh + VD, lane & 15, 0, k0);
        *(bf16x8*)(p + 5 * 512)  = load_wfrag(W1, bih + VD, bhh + VD, lane & 15, 1, k0);
        *(bf16x8*)(p + 6 * 512)  = load_wfrag(U1, nullptr, nullptr, lane & 15, 0, k0);
        *(bf16x8*)(p + 7 * 512)  = load_wfrag(U1, nullptr, nullptr, lane & 15, 1, k0);
        *(bf16x8*)(p + 8 * 512)  = load_wfrag(W2, bih + 2 * VD, bhh + 2 * VD, lane & 15, 0, k0);
        *(bf16x8*)(p + 9 * 512)  = load_wfrag(W2, bih + 2 * VD, bhh + 2 * VD, lane & 15, 1, k0);
        *(bf16x8*)(p + 10 * 512) = load_wfrag(U2, nullptr, nullptr, lane & 15, 0, k0);
        *(bf16x8*)(p + 11 * 512) = load_wfrag(U2, nullptr, nullptr, lane & 15, 1, k0);
        *(bf16x8*)(p + 12 * 512) = load_wfrag(Wlin, blin, nullptr, lane & 15, 0, k0);
        *(bf16x8*)(p + 13 * 512) = load_wfrag(Wlin, blin, nullptr, lane & 15, 1, k0);
    }
    __syncthreads();
    if (bbase >= B) return;

    const short* tp = wtab + lane * 8;   // this lane's slice of the table
#define LDF(f) (*(const bf16x8*)(tp + (f) * 512))

    // ---- initial hidden states (pad slot is a don't-care at first use:
    //      Whh fragment rows hold 0 at k=31) ----
    bf16x8 h1 = cvt_frag(load_raw(h0 + ((size_t)0 * B + bbase + cb) * VD, fo), q3);
    bf16x8 h2 = cvt_frag(load_raw(h0 + ((size_t)1 * B + bbase + cb) * VD, fo), q3);
    bf16x8 h3 = cvt_frag(load_raw(h0 + ((size_t)2 * B + bbase + cb) * VD, fo), q3);

    const float* xrow = inp + (size_t)(bbase + cb) * TD * VD;
    raw8 rx = load_raw(xrow, fo);

    // ---- t-major recurrence; weights re-read from LDS each step
    //      (lane-contiguous ds_read_b128, conflict-free). unroll 1 keeps
    //      live ranges tight for the VGPR target. ----
#pragma unroll 1
    for (int t = 0; t < TD; ++t) {
        bf16x8 ax = cvt_frag(rx, q3);
        if (t + 1 < TD)
            rx = load_raw(xrow + (t + 1) * VD, fo);
        h1 = layer_step(ax, h1, LDF(0), LDF(1), LDF(2),  LDF(3),  q3);
        h2 = layer_step(h1, h2, LDF(4), LDF(5), LDF(6),  LDF(7),  q3);
        h3 = layer_step(h2, h3, LDF(8), LDF(9), LDF(10), LDF(11), q3);
    }

    // ---- final linear + tanh + softmax (over n, i.e. across quads) ----
    {
        const f32x4 z = {0.0f, 0.0f, 0.0f, 0.0f};
        bf16x8 wl0 = LDF(12), wl1 = LDF(13);
        f32x4 c0 = __builtin_amdgcn_mfma_f32_16x16x32_bf16(wl0, h3, z, 0, 0, 0);
        f32x4 c1 = __builtin_amdgcn_mfma_f32_16x16x32_bf16(wl1, h3, z, 0, 0, 0);
        // lane (cb, q) holds y[n] for n = 8q..8q+7; n==31 (q3, c1[3]) is the
        // pad row -> tanh_pre(0) = 0, excluded from the sum (harmless in max:
        // the stabilizer just needs to be column-uniform).
        float v0 = tanh_pre(c0[0]), v1 = tanh_pre(c0[1]);
        float v2 = tanh_pre(c0[2]), v3 = tanh_pre(c0[3]);
        float v4 = tanh_pre(c1[0]), v5 = tanh_pre(c1[1]);
        float v6 = tanh_pre(c1[2]), v7 = tanh_pre(c1[3]);
        float mx = fmaxf(fmaxf(fmaxf(v0, v1), fmaxf(v2, v3)),
                         fmaxf(fmaxf(v4, v5), fmaxf(v6, v7)));
        mx = fmaxf(mx, __shfl_xor(mx, 16));
        mx = fmaxf(mx, __shfl_xor(mx, 32));
        float e0 = __expf(v0 - mx), e1 = __expf(v1 - mx);
        float e2 = __expf(v2 - mx), e3 = __expf(v3 - mx);
        float e4 = __expf(v4 - mx), e5 = __expf(v5 - mx);
        float e6 = __expf(v6 - mx);
        float e7 = q3 ? 0.0f : __expf(v7 - mx);
        float s = ((e0 + e1) + (e2 + e3)) + ((e4 + e5) + (e6 + e7));
        s += __shfl_xor(s, 16);
        s += __shfl_xor(s, 32);
        const float inv = __builtin_amdgcn_rcpf(s);
        const size_t row = (size_t)(bbase + cb);
        float* po = out + row * VD + k0;            // n = 8q..8q+7, contiguous
        f32x4u lo = {e0 * inv, e1 * inv, e2 * inv, e3 * inv};
        *(f32x4u*)po = lo;
        if (!q3) {
            f32x4u hi = {e4 * inv, e5 * inv, e6 * inv, e7 * inv};
            *(f32x4u*)(po + 4) = hi;
        } else {                                    // n = 28,29,30 only
            po[4] = e4 * inv;
            po[5] = e5 * inv;
            po[6] = e6 * inv;
        }
    }
#undef LDF
}

extern "C" void kernel_launch(void* const* d_in, const int* in_sizes, int n_in,
                              void* d_out, int out_size, void* d_ws, size_t ws_size,
                              hipStream_t stream) {
    const float* inp  = (const float*)d_in[0];
    const float* h0   = (const float*)d_in[1];
    const float* Wih  = (const float*)d_in[2];
    const float* Whh  = (const float*)d_in[3];
    const float* bih  = (const float*)d_in[4];
    const float* bhh  = (const float*)d_in[5];
    const float* Wlin = (const float*)d_in[6];
    const float* blin = (const float*)d_in[7];
    float* out = (float*)d_out;

    const int B = in_sizes[0] / (TD * VD);
    const int grid = (B + 63) / 64;      // 64 rows per block (4 waves x 16)
    rnn_mfma<<<grid, 256, 0, stream>>>(inp, h0, Wih, Whh, bih, bhh, Wlin, blin, out, B);
}

// Round 10
// 215.115 us; speedup vs baseline: 1.1885x; 1.0538x over previous
//
#include <hip/hip_runtime.h>
#include <hip/hip_bf16.h>

// Fused 3-layer tanh RNN (B=131072, T=6, V=31) + linear + tanh + softmax
// on mfma_f32_16x16x32_bf16.
//
// R15: defeat LICM on the LDS weight reads; pairwise fragment consumption.
//
// R13/R14 post-mortem: the 14 per-step LDS fragment reads are loop-
// invariant, so LICM hoisted ALL of them back into registers -- recreating
// the 56-VGPR weight set the LDS table was built to evict, then spilling
// (R13: VGPR 32 + 45MB scratch @ 8 waves/SIMD; R14: VGPR 40 + 10MB scratch
// @ 6 waves/SIMD; both WRITE_SIZE >> 15.9MB). "High occupancy without
// spill" has therefore never actually run. R15 makes it run:
//  1. asm-opaque zero offset inside the t-loop (and epilogue) makes the
//     table address unprovably invariant -> ds_read_b128 stays in-loop.
//  2. layer_step reads its 4 fragments internally, PAIRWISE (wh pair ->
//     2 MFMA -> wi pair -> 2 MFMA; same accumulate order as R7-R14 so
//     numerics are bit-identical): peak live weight frags = 2 (8 VGPRs).
// Expected peak arch pressure ~55 VGPR < 85 budget at (256,6).
//
// Evidence so far: occupancy is the ONLY lever that ever moved the memory
// rate (R13: occ 19->77% => BW 1.1->2.28 TB/s); spill ate the win. If this
// round (3x R7's resident waves, no spill) still lands ~83us, the ~83us is
// a platform floor -> declare roofline.
//
// Carried: weights in a 14KB LDS table built by wave 0 (frag f, lane l at
// f*1024 + l*16 bytes; lane-contiguous ds_read_b128, conflict-free);
// 1 tile/wave (16 rows), grid 2048; scale-folded tanh_pre
// (tanh(x) = 1 - 2*rcp(1+exp2(c)), SCL=2*log2e folded into all W/bias
// frags incl. Wlin); operand-swap recurrence D[n][b]=mfma(A=permuted-W,
// B=state) -- C output IS the next B-fragment after tanh+pack; bias rides
// the k=31 pad slot (x-frags carry 1.0 there; pad row (q3,c1[3]) forced
// to 1.0; Whh rows hold 0 at k=31). Normal stores.
//
// WATCH: WRITE_SIZE == 15.9MB (no-spill signature -- the whole point),
// VGPR 56-72, FETCH ~80MB, occ 55-65%, bank-conflict ~0.

#define VD 31
#define TD 6
#define SCL 2.8853900817779268f   // 2 * log2(e), folded into W and biases

typedef __attribute__((ext_vector_type(8))) short bf16x8;
typedef __attribute__((ext_vector_type(4))) float f32x4;
typedef __attribute__((ext_vector_type(4))) unsigned u32x4;
typedef float f32x4u __attribute__((ext_vector_type(4), aligned(4)));

struct raw8 { f32x4u a, b; };

__device__ __forceinline__ short f2bf(float f) {
    unsigned u = __float_as_uint(f);
    unsigned r = (u + 0x7fffu + ((u >> 16) & 1u)) >> 16;
    return (short)r;
}

// packed RNE fp32x2 -> bf16x2 (low = lo, high = hi)
__device__ __forceinline__ unsigned f2bf2u(float lo, float hi) {
    union { __hip_bfloat162 h2; unsigned u; } cvt;
    cvt.h2 = __float22bfloat162_rn(make_float2(lo, hi));
    return cvt.u;
}

__device__ __forceinline__ float fexp2(float x) {
#if __has_builtin(__builtin_amdgcn_exp2f)
    return __builtin_amdgcn_exp2f(x);
#else
    float r; asm("v_exp_f32 %0, %1" : "=v"(r) : "v"(x)); return r;
#endif
}

// c = 2*log2e * x (scale pre-folded into weights/biases).
// tanh(x) = 1 - 2/(e^{2x}+1); naturally saturating, no clamp needed.
__device__ __forceinline__ float tanh_pre(float c) {
    float e = fexp2(c);
    float r = __builtin_amdgcn_rcpf(e + 1.0f);
    return __builtin_fmaf(-2.0f, r, 1.0f);
}

// raw 8-float load at fo = quad3 ? 23 : quad*8 (always in-bounds, 4B aligned)
__device__ __forceinline__ raw8 load_raw(const float* __restrict__ p, int fo) {
    raw8 r;
    r.a = *(const f32x4u*)(p + fo);
    r.b = *(const f32x4u*)(p + fo + 4);
    return r;
}

// raw floats -> B-fragment (lane&15 = batch col, k = quad*8+j). Quad 3
// shifts by one and sets the k=31 pad slot to 1.0 (the bias rides there).
__device__ __forceinline__ bf16x8 cvt_frag(raw8 r, bool q3) {
    float l[8] = {r.a[0], r.a[1], r.a[2], r.a[3], r.b[0], r.b[1], r.b[2], r.b[3]};
    float s[8];
#pragma unroll
    for (int j = 0; j < 7; ++j) s[j] = q3 ? l[j + 1] : l[j];
    s[7] = q3 ? 1.0f : l[7];
    union { u32x4 u4; bf16x8 b8; } cvt;
#pragma unroll
    for (int j = 0; j < 4; ++j) cvt.u4[j] = f2bf2u(s[2 * j], s[2 * j + 1]);
    return cvt.b8;
}

// Permuted-row weight A-fragment scaled by SCL (built once by wave 0):
// A-row i of the {half} MFMA holds W row nn = 8*(i>>2)+(i&3)+4*half, so
// the C output lands pre-transposed for the next step's B-fragment.
// k=31 slot carries SCL*(b1[nn]+b2[nn]); pad row nn==31 is all zero.
__device__ __forceinline__ bf16x8 load_wfrag(const float* __restrict__ W,
                                             const float* __restrict__ b1,
                                             const float* __restrict__ b2,
                                             int i, int half, int k0) {
    const int nn = 8 * (i >> 2) + (i & 3) + 4 * half;
    bf16x8 r;
#pragma unroll
    for (int j = 0; j < 8; ++j) {
        int k = k0 + j;
        float v = 0.0f;
        if (nn < VD) {
            if (k < VD) v = W[nn * VD + k];
            else v = (b1 ? b1[nn] : 0.0f) + (b2 ? b2[nn] : 0.0f);  // k==31
        }
        r[j] = f2bf(v * SCL);
    }
    return r;
}

// One RNN layer step for one 16-row tile. Reads its 4 weight fragments
// from the LDS table PAIRWISE (peak 2 live = 8 VGPRs): wh pair -> 2 MFMA
// (h is long-ready), then wi pair -> 2 chained MFMA. Accumulate order
// matches R7-R14 (wh first) so numerics are unchanged. Returns the new h
// directly as the next B-fragment; pad row (q3, c1[3]) forced to 1.0.
__device__ __forceinline__ bf16x8 layer_step(bf16x8 x, bf16x8 h,
    const short* tp, int fbase, bool q3)
{
    const f32x4 z = {0.0f, 0.0f, 0.0f, 0.0f};
    bf16x8 wh0 = *(const bf16x8*)(tp + (fbase + 2) * 512);
    bf16x8 wh1 = *(const bf16x8*)(tp + (fbase + 3) * 512);
    f32x4 c0 = __builtin_amdgcn_mfma_f32_16x16x32_bf16(wh0, h, z, 0, 0, 0);
    f32x4 c1 = __builtin_amdgcn_mfma_f32_16x16x32_bf16(wh1, h, z, 0, 0, 0);
    bf16x8 wi0 = *(const bf16x8*)(tp + (fbase + 0) * 512);
    bf16x8 wi1 = *(const bf16x8*)(tp + (fbase + 1) * 512);
    c0 = __builtin_amdgcn_mfma_f32_16x16x32_bf16(wi0, x, c0, 0, 0, 0);
    c1 = __builtin_amdgcn_mfma_f32_16x16x32_bf16(wi1, x, c1, 0, 0, 0);
    float t0 = tanh_pre(c0[0]), t1 = tanh_pre(c0[1]);
    float t2 = tanh_pre(c0[2]), t3 = tanh_pre(c0[3]);
    float t4 = tanh_pre(c1[0]), t5 = tanh_pre(c1[1]);
    float t6 = tanh_pre(c1[2]);
    float t7 = q3 ? 1.0f : tanh_pre(c1[3]);
    union { u32x4 u4; bf16x8 b8; } cvt;
    cvt.u4[0] = f2bf2u(t0, t1);
    cvt.u4[1] = f2bf2u(t2, t3);
    cvt.u4[2] = f2bf2u(t4, t5);
    cvt.u4[3] = f2bf2u(t6, t7);
    return cvt.b8;
}

__global__ __launch_bounds__(256, 6) void rnn_mfma(
    const float* __restrict__ inp,   // [B, T, V]
    const float* __restrict__ h0,    // [L, B, V]
    const float* __restrict__ Wih,   // [L, V, V]
    const float* __restrict__ Whh,   // [L, V, V]
    const float* __restrict__ bih,   // [L, V]
    const float* __restrict__ bhh,   // [L, V]
    const float* __restrict__ Wlin,  // [V, V]
    const float* __restrict__ blin,  // [V]
    float* __restrict__ out,         // [B, V]
    int B)
{
    // 14 fragments x 64 lanes x 16B = 14336 B
    __shared__ __align__(16) short wtab[14 * 512];

    const int tid  = threadIdx.x;
    const int wave = tid >> 6;
    const int lane = tid & 63;
    const int cb   = lane & 15;          // batch column within the 16-row tile
    const int quad = lane >> 4;
    const int k0   = quad * 8;
    const bool q3  = (quad == 3);
    const int fo   = q3 ? 23 : k0;
    const int bbase = (blockIdx.x * 4 + wave) * 16;   // 16 rows per wave

    // ---- wave 0 builds the shared per-lane fragment table (one-time
    //      global gathers; 1 wave/block) ----
    if (wave == 0) {
        const float* W0 = Wih;               const float* U0 = Whh;
        const float* W1 = Wih + VD * VD;     const float* U1 = Whh + VD * VD;
        const float* W2 = Wih + 2 * VD * VD; const float* U2 = Whh + 2 * VD * VD;
        short* p = wtab + lane * 8;
        *(bf16x8*)(p + 0 * 512)  = load_wfrag(W0, bih, bhh, lane & 15, 0, k0);
        *(bf16x8*)(p + 1 * 512)  = load_wfrag(W0, bih, bhh, lane & 15, 1, k0);
        *(bf16x8*)(p + 2 * 512)  = load_wfrag(U0, nullptr, nullptr, lane & 15, 0, k0);
        *(bf16x8*)(p + 3 * 512)  = load_wfrag(U0, nullptr, nullptr, lane & 15, 1, k0);
        *(bf16x8*)(p + 4 * 512)  = load_wfrag(W1, bih + VD, bhh + VD, lane & 15, 0, k0);
        *(bf16x8*)(p + 5 * 512)  = load_wfrag(W1, bih + VD, bhh + VD, lane & 15, 1, k0);
        *(bf16x8*)(p + 6 * 512)  = load_wfrag(U1, nullptr, nullptr, lane & 15, 0, k0);
        *(bf16x8*)(p + 7 * 512)  = load_wfrag(U1, nullptr, nullptr, lane & 15, 1, k0);
        *(bf16x8*)(p + 8 * 512)  = load_wfrag(W2, bih + 2 * VD, bhh + 2 * VD, lane & 15, 0, k0);
        *(bf16x8*)(p + 9 * 512)  = load_wfrag(W2, bih + 2 * VD, bhh + 2 * VD, lane & 15, 1, k0);
        *(bf16x8*)(p + 10 * 512) = load_wfrag(U2, nullptr, nullptr, lane & 15, 0, k0);
        *(bf16x8*)(p + 11 * 512) = load_wfrag(U2, nullptr, nullptr, lane & 15, 1, k0);
        *(bf16x8*)(p + 12 * 512) = load_wfrag(Wlin, blin, nullptr, lane & 15, 0, k0);
        *(bf16x8*)(p + 13 * 512) = load_wfrag(Wlin, blin, nullptr, lane & 15, 1, k0);
    }
    __syncthreads();
    if (bbase >= B) return;

    const short* tp = wtab + lane * 8;   // this lane's slice of the table

    // ---- initial hidden states (pad slot is a don't-care at first use:
    //      Whh fragment rows hold 0 at k=31) ----
    bf16x8 h1 = cvt_frag(load_raw(h0 + ((size_t)0 * B + bbase + cb) * VD, fo), q3);
    bf16x8 h2 = cvt_frag(load_raw(h0 + ((size_t)1 * B + bbase + cb) * VD, fo), q3);
    bf16x8 h3 = cvt_frag(load_raw(h0 + ((size_t)2 * B + bbase + cb) * VD, fo), q3);

    const float* xrow = inp + (size_t)(bbase + cb) * TD * VD;
    raw8 rx = load_raw(xrow, fo);

    // ---- t-major recurrence; weight frags re-read from LDS inside each
    //      layer_step. The asm-opaque offset makes the table address
    //      unprovably loop-invariant -> LICM cannot hoist the ds_reads
    //      back into registers (the R13/R14 spill cause). ----
#pragma unroll 1
    for (int t = 0; t < TD; ++t) {
        int off = 0;
        asm volatile("" : "+v"(off));            // opaque zero
        const short* tpv = tp + off;
        bf16x8 ax = cvt_frag(rx, q3);
        if (t + 1 < TD)
            rx = load_raw(xrow + (t + 1) * VD, fo);
        h1 = layer_step(ax, h1, tpv, 0, q3);
        h2 = layer_step(h1, h2, tpv, 4, q3);
        h3 = layer_step(h2, h3, tpv, 8, q3);
    }

    // ---- final linear + tanh + softmax (over n, i.e. across quads) ----
    {
        int off = 0;
        asm volatile("" : "+v"(off));            // keep epilogue reads here
        const short* tpe = tp + off;
        const f32x4 z = {0.0f, 0.0f, 0.0f, 0.0f};
        bf16x8 wl0 = *(const bf16x8*)(tpe + 12 * 512);
        bf16x8 wl1 = *(const bf16x8*)(tpe + 13 * 512);
        f32x4 c0 = __builtin_amdgcn_mfma_f32_16x16x32_bf16(wl0, h3, z, 0, 0, 0);
        f32x4 c1 = __builtin_amdgcn_mfma_f32_16x16x32_bf16(wl1, h3, z, 0, 0, 0);
        // lane (cb, q) holds y[n] for n = 8q..8q+7; n==31 (q3, c1[3]) is the
        // pad row -> tanh_pre(0) = 0, excluded from the sum (harmless in max:
        // the stabilizer just needs to be column-uniform).
        float v0 = tanh_pre(c0[0]), v1 = tanh_pre(c0[1]);
        float v2 = tanh_pre(c0[2]), v3 = tanh_pre(c0[3]);
        float v4 = tanh_pre(c1[0]), v5 = tanh_pre(c1[1]);
        float v6 = tanh_pre(c1[2]), v7 = tanh_pre(c1[3]);
        float mx = fmaxf(fmaxf(fmaxf(v0, v1), fmaxf(v2, v3)),
                         fmaxf(fmaxf(v4, v5), fmaxf(v6, v7)));
        mx = fmaxf(mx, __shfl_xor(mx, 16));
        mx = fmaxf(mx, __shfl_xor(mx, 32));
        float e0 = __expf(v0 - mx), e1 = __expf(v1 - mx);
        float e2 = __expf(v2 - mx), e3 = __expf(v3 - mx);
        float e4 = __expf(v4 - mx), e5 = __expf(v5 - mx);
        float e6 = __expf(v6 - mx);
        float e7 = q3 ? 0.0f : __expf(v7 - mx);
        float s = ((e0 + e1) + (e2 + e3)) + ((e4 + e5) + (e6 + e7));
        s += __shfl_xor(s, 16);
        s += __shfl_xor(s, 32);
        const float inv = __builtin_amdgcn_rcpf(s);
        const size_t row = (size_t)(bbase + cb);
        float* po = out + row * VD + k0;            // n = 8q..8q+7, contiguous
        f32x4u lo = {e0 * inv, e1 * inv, e2 * inv, e3 * inv};
        *(f32x4u*)po = lo;
        if (!q3) {
            f32x4u hi = {e4 * inv, e5 * inv, e6 * inv, e7 * inv};
            *(f32x4u*)(po + 4) = hi;
        } else {                                    // n = 28,29,30 only
            po[4] = e4 * inv;
            po[5] = e5 * inv;
            po[6] = e6 * inv;
        }
    }
}

extern "C" void kernel_launch(void* const* d_in, const int* in_sizes, int n_in,
                              void* d_out, int out_size, void* d_ws, size_t ws_size,
                              hipStream_t stream) {
    const float* inp  = (const float*)d_in[0];
    const float* h0   = (const float*)d_in[1];
    const float* Wih  = (const float*)d_in[2];
    const float* Whh  = (const float*)d_in[3];
    const float* bih  = (const float*)d_in[4];
    const float* bhh  = (const float*)d_in[5];
    const float* Wlin = (const float*)d_in[6];
    const float* blin = (const float*)d_in[7];
    float* out = (float*)d_out;

    const int B = in_sizes[0] / (TD * VD);
    const int grid = (B + 63) / 64;      // 64 rows per block (4 waves x 16)
    rnn_mfma<<<grid, 256, 0, stream>>>(inp, h0, Wih, Whh, bih, bhh, Wlin, blin, out, B);
}